// Round 11
// baseline (11328.344 us; speedup 1.0000x reference)
//
#include <hip/hip_runtime.h>

#define TT 2048
#define EE 768
#define HH 512
#define GG 2048   // 4*HH
#define KK 7
#define NEGV -10000.0f
#define TAG_START 5
#define TAG_STOP 6

__device__ __forceinline__ float sigf(float x) { return 1.0f / (1.0f + __expf(-x)); }
__device__ __forceinline__ float tanh_f(float x) { return 1.0f - 2.0f / (__expf(2.0f * x) + 1.0f); }

// ---------------------------------------------------------------------------
// Kernel 1: pre[d][t][R] = embeds[row(t)] . W_ih_d[R] + (b_ih_d[R]+b_hh_d[R])
// ---------------------------------------------------------------------------
__global__ __launch_bounds__(256) void gemm_pre(
    const float* __restrict__ embeds,
    const float* __restrict__ Wf, const float* __restrict__ bif, const float* __restrict__ bhf,
    const float* __restrict__ Wb, const float* __restrict__ bib, const float* __restrict__ bhb,
    float* __restrict__ pre_f, float* __restrict__ pre_b)
{
    const int dir = blockIdx.z;
    const float* __restrict__ W  = dir ? Wb  : Wf;
    const float* __restrict__ bi = dir ? bib : bif;
    const float* __restrict__ bh = dir ? bhb : bhf;
    float* __restrict__ out = dir ? pre_b : pre_f;
    const int n0 = blockIdx.x * 128;
    const int m0 = blockIdx.y * 128;
    __shared__ __align__(16) float As[16][128];
    __shared__ __align__(16) float Bs[16][128];
    const int tid  = threadIdx.x;
    const int lrow = tid >> 1;
    const int lch  = tid & 1;
    const int tx = tid & 15, ty = tid >> 4;
    float acc[8][8];
    #pragma unroll
    for (int i = 0; i < 8; ++i)
        #pragma unroll
        for (int j = 0; j < 8; ++j) acc[i][j] = 0.0f;

    for (int k0 = 0; k0 < EE; k0 += 16) {
        const int am   = m0 + lrow;
        const int arow = dir ? (TT - 1 - am) : am;
        const float4* ap = (const float4*)(embeds + (size_t)arow * EE + k0 + lch * 8);
        const float4 a0 = ap[0], a1 = ap[1];
        const float4* bp = (const float4*)(W + (size_t)(n0 + lrow) * EE + k0 + lch * 8);
        const float4 b0 = bp[0], b1 = bp[1];
        __syncthreads();
        As[lch*8+0][lrow]=a0.x; As[lch*8+1][lrow]=a0.y; As[lch*8+2][lrow]=a0.z; As[lch*8+3][lrow]=a0.w;
        As[lch*8+4][lrow]=a1.x; As[lch*8+5][lrow]=a1.y; As[lch*8+6][lrow]=a1.z; As[lch*8+7][lrow]=a1.w;
        Bs[lch*8+0][lrow]=b0.x; Bs[lch*8+1][lrow]=b0.y; Bs[lch*8+2][lrow]=b0.z; Bs[lch*8+3][lrow]=b0.w;
        Bs[lch*8+4][lrow]=b1.x; Bs[lch*8+5][lrow]=b1.y; Bs[lch*8+6][lrow]=b1.z; Bs[lch*8+7][lrow]=b1.w;
        __syncthreads();
        #pragma unroll
        for (int k = 0; k < 16; ++k) {
            const float4 xa0 = *(const float4*)&As[k][ty*8];
            const float4 xa1 = *(const float4*)&As[k][ty*8+4];
            const float4 xb0 = *(const float4*)&Bs[k][tx*8];
            const float4 xb1 = *(const float4*)&Bs[k][tx*8+4];
            const float av[8] = {xa0.x,xa0.y,xa0.z,xa0.w,xa1.x,xa1.y,xa1.z,xa1.w};
            const float bv[8] = {xb0.x,xb0.y,xb0.z,xb0.w,xb1.x,xb1.y,xb1.z,xb1.w};
            #pragma unroll
            for (int i = 0; i < 8; ++i)
                #pragma unroll
                for (int j = 0; j < 8; ++j)
                    acc[i][j] = fmaf(av[i], bv[j], acc[i][j]);
        }
    }
    float bb[8];
    #pragma unroll
    for (int j = 0; j < 8; ++j) { const int n = n0 + tx*8 + j; bb[j] = bi[n] + bh[n]; }
    #pragma unroll
    for (int i = 0; i < 8; ++i) {
        const int m = m0 + ty*8 + i;
        float4 o0, o1;
        o0.x=acc[i][0]+bb[0]; o0.y=acc[i][1]+bb[1]; o0.z=acc[i][2]+bb[2]; o0.w=acc[i][3]+bb[3];
        o1.x=acc[i][4]+bb[4]; o1.y=acc[i][5]+bb[5]; o1.z=acc[i][6]+bb[6]; o1.w=acc[i][7]+bb[7];
        float4* op = (float4*)(out + (size_t)m * GG + n0 + tx*8);
        op[0] = o0; op[1] = o1;
    }
}

// ---------------------------------------------------------------------------
// Kernel 2: sequential BiLSTM scan — W_hh in LDS as bf16 (R9-verified clean:
// no spill, 3.3e4 bank conflicts, 18 MB writes). R9 finding: per-step 3.8 µs
// was SYNC, not compute — 16 same-line agent-scope fetch_adds serialize at
// the coherent point. This round: single-writer flags (no RMW).
//   producer (per WG): fence(release,agent); flag[w] = s+1 (relaxed store)
//   consumer: wave0 lanes 0..15 poll 16 flags in parallel (relaxed) until
//             __all(fl >= s); syncthreads; fence(acquire,agent); read h.
// hs history store moved AFTER the flag store (off the critical path).
// ---------------------------------------------------------------------------
__global__ __launch_bounds__(512) void lstm_scan(
    const float* __restrict__ Whh_f, const float* __restrict__ Whh_b,
    const float* __restrict__ h0, const float* __restrict__ c0,
    const float* __restrict__ pre_f, const float* __restrict__ pre_b,
    float* __restrict__ hs_f, float* __restrict__ hs_b,
    float* __restrict__ hbuf, int* __restrict__ cnt)
{
    const int bx = blockIdx.x;
    const int d = bx >> 4;
    const int w = bx & 15;
    const float* __restrict__ Whh = d ? Whh_b : Whh_f;
    const float* __restrict__ pre = d ? pre_b : pre_f;
    float* __restrict__ hs = d ? hs_b : hs_f;
    float* __restrict__ hb = hbuf + d * 2 * HH;   // ping-pong [2][512] per dir
    int* flg = cnt + d * 16 * 32;                 // 16 flags, 128 B apart
    const int tid = threadIdx.x;
    const int v = tid >> 6;
    const int l = tid & 63;

    __shared__ __align__(16) unsigned short wlds[128][512];  // 128 KB bf16
    __shared__ float zsum[128];

    // one-time: load W_hh shard, fp32->bf16 (RNE), stage in LDS.
    for (int i = tid; i < 128 * 128; i += 512) {        // float4 granules
        const int rho = i >> 7;
        const int c4  = i & 127;
        const int R = (rho >> 5) * HH + w * 32 + (rho & 31);
        const float4 wv = *(const float4*)(Whh + (size_t)R * HH + c4 * 4);
        const unsigned int b0 = __float_as_uint(wv.x);
        const unsigned int b1 = __float_as_uint(wv.y);
        const unsigned int b2 = __float_as_uint(wv.z);
        const unsigned int b3 = __float_as_uint(wv.w);
        const unsigned int r0 = (b0 + 0x7FFFu + ((b0 >> 16) & 1u)) >> 16;
        const unsigned int r1 = (b1 + 0x7FFFu + ((b1 >> 16) & 1u)) >> 16;
        const unsigned int r2 = (b2 + 0x7FFFu + ((b2 >> 16) & 1u)) >> 16;
        const unsigned int r3 = (b3 + 0x7FFFu + ((b3 >> 16) & 1u)) >> 16;
        uint2 pk;
        pk.x = r0 | (r1 << 16);
        pk.y = r2 | (r3 << 16);
        *(uint2*)&wlds[rho][c4 * 4] = pk;
    }

    const bool comb = (v == 0) && (l < 32);
    float creg = comb ? c0[d * HH + w * 32 + l] : 0.0f;
    float hreg[8];
    {
        const float4* hp = (const float4*)(h0 + d * HH + l * 8);
        const float4 ha = hp[0], hc = hp[1];
        hreg[0]=ha.x; hreg[1]=ha.y; hreg[2]=ha.z; hreg[3]=ha.w;
        hreg[4]=hc.x; hreg[5]=hc.y; hreg[6]=hc.z; hreg[7]=hc.w;
    }
    long long budget = 50000000LL; // watchdog: broken sync -> garbage, not hang
    __syncthreads();               // LDS weights ready

    for (int s = 0; s < TT; ++s) {
        // prefetch pre-activations (independent of h) before polling
        float pg0 = 0.f, pg1 = 0.f, pg2 = 0.f, pg3 = 0.f;
        if (comb) {
            const float* pp = pre + (size_t)s * GG + w * 32 + l;
            pg0 = pp[0]; pg1 = pp[HH]; pg2 = pp[2*HH]; pg3 = pp[3*HH];
        }
        if (s > 0) {
            if (v == 0) {
                // lanes 0..15 poll their producer's flag in parallel (no RMW,
                // no per-iteration invalidate)
                for (;;) {
                    int fl = 0x7fffffff;
                    if (l < 16)
                        fl = __hip_atomic_load(flg + l * 32, __ATOMIC_RELAXED,
                                               __HIP_MEMORY_SCOPE_AGENT);
                    if (__all(fl >= s)) break;
                    if (--budget < 0) break;
                    __builtin_amdgcn_s_sleep(1);
                }
            }
            __syncthreads();
            __builtin_amdgcn_fence(__ATOMIC_ACQUIRE, "agent");
            const float4* hp = (const float4*)(hb + (s & 1) * HH + l * 8);
            const float4 ha = hp[0], hc = hp[1];
            hreg[0]=ha.x; hreg[1]=ha.y; hreg[2]=ha.z; hreg[3]=ha.w;
            hreg[4]=hc.x; hreg[5]=hc.y; hreg[6]=hc.z; hreg[7]=hc.w;
        }
        // matvec: 4 passes x 4 rows (R9-verified spill-free schedule)
        #pragma unroll
        for (int p = 0; p < 4; ++p) {
            float acc[4];
            #pragma unroll
            for (int j = 0; j < 4; ++j) {
                const int rho = v * 16 + p * 4 + j;
                const uint4 q = *(const uint4*)&wlds[rho][l * 8];
                float a;
                a = __uint_as_float(q.x << 16)              * hreg[0];
                a = fmaf(__uint_as_float(q.x & 0xFFFF0000u), hreg[1], a);
                a = fmaf(__uint_as_float(q.y << 16),         hreg[2], a);
                a = fmaf(__uint_as_float(q.y & 0xFFFF0000u), hreg[3], a);
                a = fmaf(__uint_as_float(q.z << 16),         hreg[4], a);
                a = fmaf(__uint_as_float(q.z & 0xFFFF0000u), hreg[5], a);
                a = fmaf(__uint_as_float(q.w << 16),         hreg[6], a);
                a = fmaf(__uint_as_float(q.w & 0xFFFF0000u), hreg[7], a);
                acc[j] = a;
            }
            #pragma unroll
            for (int j = 0; j < 4; ++j) acc[j] += __shfl_xor(acc[j], 1);
            float t2_0 = (l & 1) ? acc[2] : acc[0];
            float t2_1 = (l & 1) ? acc[3] : acc[1];
            t2_0 += __shfl_xor(t2_0, 2);
            t2_1 += __shfl_xor(t2_1, 2);
            float t = (l & 2) ? t2_1 : t2_0;
            t += __shfl_xor(t, 4);
            t += __shfl_xor(t, 8);
            t += __shfl_xor(t, 16);
            t += __shfl_xor(t, 32);
            if (l < 4) {
                const int j = ((l & 1) << 1) | ((l & 2) >> 1);
                zsum[v * 16 + p * 4 + j] = t;
            }
            __builtin_amdgcn_sched_barrier(0);
        }
        __syncthreads();
        float hn = 0.0f;
        if (comb) {
            const float zi = zsum[l]      + pg0;
            const float zf = zsum[32 + l] + pg1;
            const float zg = zsum[64 + l] + pg2;
            const float zo = zsum[96 + l] + pg3;
            const float ig = sigf(zi), fg = sigf(zf), gg = tanh_f(zg), og = sigf(zo);
            creg = fg * creg + ig * gg;
            hn = og * tanh_f(creg);
            hb[((s + 1) & 1) * HH + w * 32 + l] = hn;   // the only pre-fence store
        }
        if (v == 0) {
            // wave-level release: waits only for this wave's hb store
            __builtin_amdgcn_fence(__ATOMIC_RELEASE, "agent");
            if (l == 0)
                __hip_atomic_store(flg + w * 32, s + 1, __ATOMIC_RELAXED,
                                   __HIP_MEMORY_SCOPE_AGENT);
        }
        if (comb)
            hs[(size_t)s * HH + w * 32 + l] = hn;       // off the critical path
    }
}

// ---------------------------------------------------------------------------
// Kernel 3: feats[t][k] = [hs_f[t], hs_b[T-1-t]] . W_out[k] + b_out[k]
// ---------------------------------------------------------------------------
__global__ __launch_bounds__(256) void feats_k(
    const float* __restrict__ hsf, const float* __restrict__ hsb,
    const float* __restrict__ Wout, const float* __restrict__ bout,
    float* __restrict__ feats)
{
    const int wv = threadIdx.x >> 6;
    const int l  = threadIdx.x & 63;
    const int t  = blockIdx.x * 4 + wv;
    float acc[KK];
    #pragma unroll
    for (int k = 0; k < KK; ++k) acc[k] = 0.0f;
    const float* hf  = hsf + (size_t)t * HH;
    const float* hbp = hsb + (size_t)(TT - 1 - t) * HH;
    for (int c = l; c < HH; c += 64) {
        const float xf = hf[c];
        const float xb = hbp[c];
        #pragma unroll
        for (int k = 0; k < KK; ++k)
            acc[k] += xf * Wout[k * 1024 + c] + xb * Wout[k * 1024 + HH + c];
    }
    #pragma unroll
    for (int k = 0; k < KK; ++k) {
        #pragma unroll
        for (int m = 1; m <= 32; m <<= 1) acc[k] += __shfl_xor(acc[k], m);
    }
    if (l == 0) {
        #pragma unroll
        for (int k = 0; k < KK; ++k) feats[t * KK + k] = acc[k] + bout[k];
    }
}

// ---------------------------------------------------------------------------
// Kernel 4: Viterbi. 1 block, 64 threads. lane = kn*8+kp (valid kn,kp < 7).
// ---------------------------------------------------------------------------
__global__ __launch_bounds__(64) void viterbi_k(
    const float* __restrict__ feats, const float* __restrict__ trans,
    float* __restrict__ out)
{
    __shared__ float fl[TT * KK];
    __shared__ unsigned char bp[TT * KK];
    __shared__ unsigned char path[TT];
    const int l = threadIdx.x;
    for (int i = l; i < TT * KK; i += 64) fl[i] = feats[i];
    const int kn = l >> 3, kp = l & 7;
    const float tr = (kn < 7 && kp < 7) ? trans[kn * 7 + kp] : -1e30f;
    float fv = (kp == 7) ? -1e30f : ((kp == TAG_START) ? 0.0f : NEGV);
    const int srcl = (l & 7) << 3;
    __syncthreads();
    for (int t = 0; t < TT; ++t) {
        float vv = fv + tr;
        int bi = kp;
        #pragma unroll
        for (int m = 1; m <= 4; m <<= 1) {
            const float ov = __shfl_xor(vv, m);
            const int   oi = __shfl_xor(bi, m);
            if (ov > vv || (ov == vv && oi < bi)) { vv = ov; bi = oi; }
        }
        const float feat = fl[t * KK + (kn < 7 ? kn : 6)];
        const float fvn = vv + feat;
        if (kp == 0 && kn < 7) bp[t * KK + kn] = (unsigned char)bi;
        fv = __shfl(fvn, srcl);
        if ((l & 7) == 7) fv = -1e30f;
    }
    float tv = (l < 7) ? (fv + trans[TAG_STOP * 7 + l]) : -1e30f;
    int ti = l & 7;
    #pragma unroll
    for (int m = 1; m <= 4; m <<= 1) {
        const float ov = __shfl_xor(tv, m);
        const int   oi = __shfl_xor(ti, m);
        if (ov > tv || (ov == tv && oi < ti)) { tv = ov; ti = oi; }
    }
    __syncthreads();
    if (l == 0) {
        out[0] = tv;                     // path_score
        int tag = ti;
        path[TT - 1] = (unsigned char)tag;
        for (int t = TT - 1; t >= 1; --t) {
            tag = bp[t * KK + tag];
            path[t - 1] = (unsigned char)tag;
        }
    }
    __syncthreads();
    for (int t = l; t < TT; t += 64) out[1 + t] = (float)path[t];
}

// ---------------------------------------------------------------------------
extern "C" void kernel_launch(void* const* d_in, const int* in_sizes, int n_in,
                              void* d_out, int out_size, void* d_ws, size_t ws_size,
                              hipStream_t stream) {
    const float* embeds = (const float*)d_in[0];
    const float* h0     = (const float*)d_in[1];
    const float* c0     = (const float*)d_in[2];
    const float* Wihf   = (const float*)d_in[3];
    const float* Whhf   = (const float*)d_in[4];
    const float* bihf   = (const float*)d_in[5];
    const float* bhhf   = (const float*)d_in[6];
    const float* Wihb   = (const float*)d_in[7];
    const float* Whhb   = (const float*)d_in[8];
    const float* bihb   = (const float*)d_in[9];
    const float* bhhb   = (const float*)d_in[10];
    const float* Wout   = (const float*)d_in[11];
    const float* bout   = (const float*)d_in[12];
    const float* trans  = (const float*)d_in[13];
    float* out = (float*)d_out;

    float* ws    = (float*)d_ws;
    float* pre_f = ws;                                   // T*G floats
    float* pre_b = pre_f + (size_t)TT * GG;
    float* hs_f  = pre_b + (size_t)TT * GG;              // T*H
    float* hs_b  = hs_f + (size_t)TT * HH;
    float* feats = hs_b + (size_t)TT * HH;               // T*K
    float* hbuf  = feats + (size_t)TT * KK;              // 2*2*H
    int*   cnt   = (int*)(hbuf + 4 * HH);                // 2*16 flags, 128B apart

    hipMemsetAsync(cnt, 0, (size_t)2 * 16 * 32 * sizeof(int), stream);
    gemm_pre<<<dim3(16, 16, 2), 256, 0, stream>>>(
        embeds, Wihf, bihf, bhhf, Wihb, bihb, bhhb, pre_f, pre_b);
    lstm_scan<<<32, 512, 0, stream>>>(
        Whhf, Whhb, h0, c0, pre_f, pre_b, hs_f, hs_b, hbuf, cnt);
    feats_k<<<TT / 4, 256, 0, stream>>>(hs_f, hs_b, Wout, bout, feats);
    viterbi_k<<<1, 64, 0, stream>>>(feats, trans, out);
}

// Round 12
// 8285.831 us; speedup vs baseline: 1.3672x; 1.3672x over previous
//
#include <hip/hip_runtime.h>

#define TT 2048
#define EE 768
#define HH 512
#define GG 2048   // 4*HH
#define KK 7
#define NEGV -10000.0f
#define TAG_START 5
#define TAG_STOP 6

__device__ __forceinline__ float sigf(float x) { return 1.0f / (1.0f + __expf(-x)); }
__device__ __forceinline__ float tanh_f(float x) { return 1.0f - 2.0f / (__expf(2.0f * x) + 1.0f); }

// ---------------------------------------------------------------------------
// Kernel 1: pre[d][t][R] = embeds[row(t)] . W_ih_d[R] + (b_ih_d[R]+b_hh_d[R])
// ---------------------------------------------------------------------------
__global__ __launch_bounds__(256) void gemm_pre(
    const float* __restrict__ embeds,
    const float* __restrict__ Wf, const float* __restrict__ bif, const float* __restrict__ bhf,
    const float* __restrict__ Wb, const float* __restrict__ bib, const float* __restrict__ bhb,
    float* __restrict__ pre_f, float* __restrict__ pre_b)
{
    const int dir = blockIdx.z;
    const float* __restrict__ W  = dir ? Wb  : Wf;
    const float* __restrict__ bi = dir ? bib : bif;
    const float* __restrict__ bh = dir ? bhb : bhf;
    float* __restrict__ out = dir ? pre_b : pre_f;
    const int n0 = blockIdx.x * 128;
    const int m0 = blockIdx.y * 128;
    __shared__ __align__(16) float As[16][128];
    __shared__ __align__(16) float Bs[16][128];
    const int tid  = threadIdx.x;
    const int lrow = tid >> 1;
    const int lch  = tid & 1;
    const int tx = tid & 15, ty = tid >> 4;
    float acc[8][8];
    #pragma unroll
    for (int i = 0; i < 8; ++i)
        #pragma unroll
        for (int j = 0; j < 8; ++j) acc[i][j] = 0.0f;

    for (int k0 = 0; k0 < EE; k0 += 16) {
        const int am   = m0 + lrow;
        const int arow = dir ? (TT - 1 - am) : am;
        const float4* ap = (const float4*)(embeds + (size_t)arow * EE + k0 + lch * 8);
        const float4 a0 = ap[0], a1 = ap[1];
        const float4* bp = (const float4*)(W + (size_t)(n0 + lrow) * EE + k0 + lch * 8);
        const float4 b0 = bp[0], b1 = bp[1];
        __syncthreads();
        As[lch*8+0][lrow]=a0.x; As[lch*8+1][lrow]=a0.y; As[lch*8+2][lrow]=a0.z; As[lch*8+3][lrow]=a0.w;
        As[lch*8+4][lrow]=a1.x; As[lch*8+5][lrow]=a1.y; As[lch*8+6][lrow]=a1.z; As[lch*8+7][lrow]=a1.w;
        Bs[lch*8+0][lrow]=b0.x; Bs[lch*8+1][lrow]=b0.y; Bs[lch*8+2][lrow]=b0.z; Bs[lch*8+3][lrow]=b0.w;
        Bs[lch*8+4][lrow]=b1.x; Bs[lch*8+5][lrow]=b1.y; Bs[lch*8+6][lrow]=b1.z; Bs[lch*8+7][lrow]=b1.w;
        __syncthreads();
        #pragma unroll
        for (int k = 0; k < 16; ++k) {
            const float4 xa0 = *(const float4*)&As[k][ty*8];
            const float4 xa1 = *(const float4*)&As[k][ty*8+4];
            const float4 xb0 = *(const float4*)&Bs[k][tx*8];
            const float4 xb1 = *(const float4*)&Bs[k][tx*8+4];
            const float av[8] = {xa0.x,xa0.y,xa0.z,xa0.w,xa1.x,xa1.y,xa1.z,xa1.w};
            const float bv[8] = {xb0.x,xb0.y,xb0.z,xb0.w,xb1.x,xb1.y,xb1.z,xb1.w};
            #pragma unroll
            for (int i = 0; i < 8; ++i)
                #pragma unroll
                for (int j = 0; j < 8; ++j)
                    acc[i][j] = fmaf(av[i], bv[j], acc[i][j]);
        }
    }
    float bb[8];
    #pragma unroll
    for (int j = 0; j < 8; ++j) { const int n = n0 + tx*8 + j; bb[j] = bi[n] + bh[n]; }
    #pragma unroll
    for (int i = 0; i < 8; ++i) {
        const int m = m0 + ty*8 + i;
        float4 o0, o1;
        o0.x=acc[i][0]+bb[0]; o0.y=acc[i][1]+bb[1]; o0.z=acc[i][2]+bb[2]; o0.w=acc[i][3]+bb[3];
        o1.x=acc[i][4]+bb[4]; o1.y=acc[i][5]+bb[5]; o1.z=acc[i][6]+bb[6]; o1.w=acc[i][7]+bb[7];
        float4* op = (float4*)(out + (size_t)m * GG + n0 + tx*8);
        op[0] = o0; op[1] = o1;
    }
}

// ---------------------------------------------------------------------------
// Kernel 2: sequential BiLSTM scan — W_hh in LDS as bf16 (R9-verified clean).
// Sync evolution: R9 = 16-way same-line RMW + per-poll acquire (3.79 µs/step);
// R11 = single-writer flags + full agent fences every step (5.07 µs/step —
// fences/invalidates are the expensive primitive, +30 MB FETCH).
// R12: coherent-bypass message passing — NO fences anywhere in the loop:
//   * hb accessed ONLY via relaxed agent atomics (device-coherent bypass:
//     consumers can never see a stale L2 line -> no acquire/invalidate)
//   * producer: comb-lane relaxed atomic h-stores, then tid0 RELEASE atomic
//     store to its OWN padded flag (same wave -> vmcnt-ordered; no RMW chain)
//   * hs history = nontemporal store AFTER the flag (off critical path, and
//     keeps L2 clean so the release's implicit writeback is ~free)
//   * poll: wave0 lanes 0..15 relaxed-load 16 flags (one vector op, no inval)
// ---------------------------------------------------------------------------
__global__ __launch_bounds__(512) void lstm_scan(
    const float* __restrict__ Whh_f, const float* __restrict__ Whh_b,
    const float* __restrict__ h0, const float* __restrict__ c0,
    const float* __restrict__ pre_f, const float* __restrict__ pre_b,
    float* __restrict__ hs_f, float* __restrict__ hs_b,
    float* __restrict__ hbuf, int* __restrict__ cnt)
{
    const int bx = blockIdx.x;
    const int d = bx >> 4;
    const int w = bx & 15;
    const float* __restrict__ Whh = d ? Whh_b : Whh_f;
    const float* __restrict__ pre = d ? pre_b : pre_f;
    float* __restrict__ hs = d ? hs_b : hs_f;
    float* hb = hbuf + d * 2 * HH;                // ping-pong [2][512] per dir
    int* flg = cnt + d * 16 * 32;                 // 16 flags, 128 B apart
    const int tid = threadIdx.x;
    const int v = tid >> 6;
    const int l = tid & 63;

    __shared__ __align__(16) unsigned short wlds[128][512];  // 128 KB bf16
    __shared__ float zsum[128];

    // one-time: load W_hh shard, fp32->bf16 (RNE), stage in LDS.
    for (int i = tid; i < 128 * 128; i += 512) {        // float4 granules
        const int rho = i >> 7;
        const int c4  = i & 127;
        const int R = (rho >> 5) * HH + w * 32 + (rho & 31);
        const float4 wv = *(const float4*)(Whh + (size_t)R * HH + c4 * 4);
        const unsigned int b0 = __float_as_uint(wv.x);
        const unsigned int b1 = __float_as_uint(wv.y);
        const unsigned int b2 = __float_as_uint(wv.z);
        const unsigned int b3 = __float_as_uint(wv.w);
        const unsigned int r0 = (b0 + 0x7FFFu + ((b0 >> 16) & 1u)) >> 16;
        const unsigned int r1 = (b1 + 0x7FFFu + ((b1 >> 16) & 1u)) >> 16;
        const unsigned int r2 = (b2 + 0x7FFFu + ((b2 >> 16) & 1u)) >> 16;
        const unsigned int r3 = (b3 + 0x7FFFu + ((b3 >> 16) & 1u)) >> 16;
        uint2 pk;
        pk.x = r0 | (r1 << 16);
        pk.y = r2 | (r3 << 16);
        *(uint2*)&wlds[rho][c4 * 4] = pk;
    }

    const bool comb = (v == 0) && (l < 32);
    float creg = comb ? c0[d * HH + w * 32 + l] : 0.0f;
    float hreg[8];
    {
        const float4* hp = (const float4*)(h0 + d * HH + l * 8);
        const float4 ha = hp[0], hc = hp[1];
        hreg[0]=ha.x; hreg[1]=ha.y; hreg[2]=ha.z; hreg[3]=ha.w;
        hreg[4]=hc.x; hreg[5]=hc.y; hreg[6]=hc.z; hreg[7]=hc.w;
    }
    long long budget = 50000000LL; // watchdog: broken sync -> garbage, not hang
    __syncthreads();               // LDS weights ready

    for (int s = 0; s < TT; ++s) {
        // prefetch pre-activations (independent of h) before polling
        float pg0 = 0.f, pg1 = 0.f, pg2 = 0.f, pg3 = 0.f;
        if (comb) {
            const float* pp = pre + (size_t)s * GG + w * 32 + l;
            pg0 = pp[0]; pg1 = pp[HH]; pg2 = pp[2*HH]; pg3 = pp[3*HH];
        }
        if (s > 0) {
            if (v == 0) {
                // lanes 0..15 poll 16 single-writer flags (relaxed bypass
                // loads: served at the coherent point, no invalidation)
                for (;;) {
                    int fl = 0x7fffffff;
                    if (l < 16)
                        fl = __hip_atomic_load(flg + l * 32, __ATOMIC_RELAXED,
                                               __HIP_MEMORY_SCOPE_AGENT);
                    if (__all(fl >= s)) break;
                    if (--budget < 0) break;
                    __builtin_amdgcn_s_sleep(1);
                }
            }
            __syncthreads();
            // h read: relaxed agent atomic loads -> always fresh (bypass)
            const unsigned long long* hp =
                (const unsigned long long*)(hb + (s & 1) * HH + l * 8);
            #pragma unroll
            for (int i = 0; i < 4; ++i) {
                const unsigned long long u = __hip_atomic_load(
                    hp + i, __ATOMIC_RELAXED, __HIP_MEMORY_SCOPE_AGENT);
                hreg[2*i]   = __uint_as_float((unsigned int)u);
                hreg[2*i+1] = __uint_as_float((unsigned int)(u >> 32));
            }
        }
        // matvec: 4 passes x 4 rows (R9-verified spill-free schedule)
        #pragma unroll
        for (int p = 0; p < 4; ++p) {
            float acc[4];
            #pragma unroll
            for (int j = 0; j < 4; ++j) {
                const int rho = v * 16 + p * 4 + j;
                const uint4 q = *(const uint4*)&wlds[rho][l * 8];
                float a;
                a = __uint_as_float(q.x << 16)              * hreg[0];
                a = fmaf(__uint_as_float(q.x & 0xFFFF0000u), hreg[1], a);
                a = fmaf(__uint_as_float(q.y << 16),         hreg[2], a);
                a = fmaf(__uint_as_float(q.y & 0xFFFF0000u), hreg[3], a);
                a = fmaf(__uint_as_float(q.z << 16),         hreg[4], a);
                a = fmaf(__uint_as_float(q.z & 0xFFFF0000u), hreg[5], a);
                a = fmaf(__uint_as_float(q.w << 16),         hreg[6], a);
                a = fmaf(__uint_as_float(q.w & 0xFFFF0000u), hreg[7], a);
                acc[j] = a;
            }
            #pragma unroll
            for (int j = 0; j < 4; ++j) acc[j] += __shfl_xor(acc[j], 1);
            float t2_0 = (l & 1) ? acc[2] : acc[0];
            float t2_1 = (l & 1) ? acc[3] : acc[1];
            t2_0 += __shfl_xor(t2_0, 2);
            t2_1 += __shfl_xor(t2_1, 2);
            float t = (l & 2) ? t2_1 : t2_0;
            t += __shfl_xor(t, 4);
            t += __shfl_xor(t, 8);
            t += __shfl_xor(t, 16);
            t += __shfl_xor(t, 32);
            if (l < 4) {
                const int j = ((l & 1) << 1) | ((l & 2) >> 1);
                zsum[v * 16 + p * 4 + j] = t;
            }
            __builtin_amdgcn_sched_barrier(0);
        }
        __syncthreads();
        float hn = 0.0f;
        if (comb) {
            const float zi = zsum[l]      + pg0;
            const float zf = zsum[32 + l] + pg1;
            const float zg = zsum[64 + l] + pg2;
            const float zo = zsum[96 + l] + pg3;
            const float ig = sigf(zi), fg = sigf(zf), gg = tanh_f(zg), og = sigf(zo);
            creg = fg * creg + ig * gg;
            hn = og * tanh_f(creg);
            // h publish: relaxed agent atomic store (write-through, coherent)
            __hip_atomic_store(hb + ((s + 1) & 1) * HH + w * 32 + l, hn,
                               __ATOMIC_RELAXED, __HIP_MEMORY_SCOPE_AGENT);
        }
        if (tid == 0) {
            // release store on OWN flag: same wave as the h stores above ->
            // vmcnt-ordered; L2 kept clean so implicit writeback is ~free
            __hip_atomic_store(flg + w * 32, s + 1, __ATOMIC_RELEASE,
                               __HIP_MEMORY_SCOPE_AGENT);
        }
        if (comb)  // history write off the critical path, nontemporal (L2-clean)
            __builtin_nontemporal_store(hn, &hs[(size_t)s * HH + w * 32 + l]);
    }
}

// ---------------------------------------------------------------------------
// Kernel 3: feats[t][k] = [hs_f[t], hs_b[T-1-t]] . W_out[k] + b_out[k]
// ---------------------------------------------------------------------------
__global__ __launch_bounds__(256) void feats_k(
    const float* __restrict__ hsf, const float* __restrict__ hsb,
    const float* __restrict__ Wout, const float* __restrict__ bout,
    float* __restrict__ feats)
{
    const int wv = threadIdx.x >> 6;
    const int l  = threadIdx.x & 63;
    const int t  = blockIdx.x * 4 + wv;
    float acc[KK];
    #pragma unroll
    for (int k = 0; k < KK; ++k) acc[k] = 0.0f;
    const float* hf  = hsf + (size_t)t * HH;
    const float* hbp = hsb + (size_t)(TT - 1 - t) * HH;
    for (int c = l; c < HH; c += 64) {
        const float xf = hf[c];
        const float xb = hbp[c];
        #pragma unroll
        for (int k = 0; k < KK; ++k)
            acc[k] += xf * Wout[k * 1024 + c] + xb * Wout[k * 1024 + HH + c];
    }
    #pragma unroll
    for (int k = 0; k < KK; ++k) {
        #pragma unroll
        for (int m = 1; m <= 32; m <<= 1) acc[k] += __shfl_xor(acc[k], m);
    }
    if (l == 0) {
        #pragma unroll
        for (int k = 0; k < KK; ++k) feats[t * KK + k] = acc[k] + bout[k];
    }
}

// ---------------------------------------------------------------------------
// Kernel 4: Viterbi. 1 block, 64 threads. lane = kn*8+kp (valid kn,kp < 7).
// ---------------------------------------------------------------------------
__global__ __launch_bounds__(64) void viterbi_k(
    const float* __restrict__ feats, const float* __restrict__ trans,
    float* __restrict__ out)
{
    __shared__ float fl[TT * KK];
    __shared__ unsigned char bp[TT * KK];
    __shared__ unsigned char path[TT];
    const int l = threadIdx.x;
    for (int i = l; i < TT * KK; i += 64) fl[i] = feats[i];
    const int kn = l >> 3, kp = l & 7;
    const float tr = (kn < 7 && kp < 7) ? trans[kn * 7 + kp] : -1e30f;
    float fv = (kp == 7) ? -1e30f : ((kp == TAG_START) ? 0.0f : NEGV);
    const int srcl = (l & 7) << 3;
    __syncthreads();
    for (int t = 0; t < TT; ++t) {
        float vv = fv + tr;
        int bi = kp;
        #pragma unroll
        for (int m = 1; m <= 4; m <<= 1) {
            const float ov = __shfl_xor(vv, m);
            const int   oi = __shfl_xor(bi, m);
            if (ov > vv || (ov == vv && oi < bi)) { vv = ov; bi = oi; }
        }
        const float feat = fl[t * KK + (kn < 7 ? kn : 6)];
        const float fvn = vv + feat;
        if (kp == 0 && kn < 7) bp[t * KK + kn] = (unsigned char)bi;
        fv = __shfl(fvn, srcl);
        if ((l & 7) == 7) fv = -1e30f;
    }
    float tv = (l < 7) ? (fv + trans[TAG_STOP * 7 + l]) : -1e30f;
    int ti = l & 7;
    #pragma unroll
    for (int m = 1; m <= 4; m <<= 1) {
        const float ov = __shfl_xor(tv, m);
        const int   oi = __shfl_xor(ti, m);
        if (ov > tv || (ov == tv && oi < ti)) { tv = ov; ti = oi; }
    }
    __syncthreads();
    if (l == 0) {
        out[0] = tv;                     // path_score
        int tag = ti;
        path[TT - 1] = (unsigned char)tag;
        for (int t = TT - 1; t >= 1; --t) {
            tag = bp[t * KK + tag];
            path[t - 1] = (unsigned char)tag;
        }
    }
    __syncthreads();
    for (int t = l; t < TT; t += 64) out[1 + t] = (float)path[t];
}

// ---------------------------------------------------------------------------
extern "C" void kernel_launch(void* const* d_in, const int* in_sizes, int n_in,
                              void* d_out, int out_size, void* d_ws, size_t ws_size,
                              hipStream_t stream) {
    const float* embeds = (const float*)d_in[0];
    const float* h0     = (const float*)d_in[1];
    const float* c0     = (const float*)d_in[2];
    const float* Wihf   = (const float*)d_in[3];
    const float* Whhf   = (const float*)d_in[4];
    const float* bihf   = (const float*)d_in[5];
    const float* bhhf   = (const float*)d_in[6];
    const float* Wihb   = (const float*)d_in[7];
    const float* Whhb   = (const float*)d_in[8];
    const float* bihb   = (const float*)d_in[9];
    const float* bhhb   = (const float*)d_in[10];
    const float* Wout   = (const float*)d_in[11];
    const float* bout   = (const float*)d_in[12];
    const float* trans  = (const float*)d_in[13];
    float* out = (float*)d_out;

    float* ws    = (float*)d_ws;
    float* pre_f = ws;                                   // T*G floats
    float* pre_b = pre_f + (size_t)TT * GG;
    float* hs_f  = pre_b + (size_t)TT * GG;              // T*H
    float* hs_b  = hs_f + (size_t)TT * HH;
    float* feats = hs_b + (size_t)TT * HH;               // T*K
    float* hbuf  = feats + (size_t)TT * KK;              // 2*2*H
    int*   cnt   = (int*)(hbuf + 4 * HH);                // 2*16 flags, 128B apart

    hipMemsetAsync(cnt, 0, (size_t)2 * 16 * 32 * sizeof(int), stream);
    gemm_pre<<<dim3(16, 16, 2), 256, 0, stream>>>(
        embeds, Wihf, bihf, bhhf, Wihb, bihb, bhhb, pre_f, pre_b);
    lstm_scan<<<32, 512, 0, stream>>>(
        Whhf, Whhb, h0, c0, pre_f, pre_b, hs_f, hs_b, hbuf, cnt);
    feats_k<<<TT / 4, 256, 0, stream>>>(hs_f, hs_b, Wout, bout, feats);
    viterbi_k<<<1, 64, 0, stream>>>(feats, trans, out);
}